// Round 5
// baseline (961.394 us; speedup 1.0000x reference)
//
#include <hip/hip_runtime.h>
#include <hip/hip_cooperative_groups.h>
#include <stdint.h>

namespace cg = cooperative_groups;

// Problem constants (B=4, L=2048, D=2048)
#define B_DIM 4
#define L_DIM 2048
#define D_DIM 2048
#define M_DIM 8192              // B*L token rows
#define K_DIM 2048
#define N_DIM 2048
#define WELEM (D_DIM * D_DIM)   // 4194304 elements per weight
#define CHUNK 32
#define NCH (L_DIM / CHUNK)     // 64 chunks per sequence

// GEMM tiling: block 128x256, 4 waves of 64x128, BK=64 bytes
#define BM 128
#define BN 256
#define BKB 64

typedef int v4i __attribute__((ext_vector_type(4)));
typedef unsigned short bfraw;   // bf16 bit pattern

#define AS1 __attribute__((address_space(1)))
#define AS3 __attribute__((address_space(3)))

__device__ __forceinline__ void gl_lds16(const void* g, void* l) {
    // async global->LDS, 16B per lane; LDS dst = wave-uniform base + lane*16
    __builtin_amdgcn_global_load_lds((AS1 void*)g, (AS3 void*)l, 16, 0, 0);
}

__device__ __forceinline__ float sigmoidf_(float x) { return 1.0f / (1.0f + expf(-x)); }

__device__ __forceinline__ float bf2f(bfraw u) {
    union { unsigned int i; float f; } c; c.i = ((unsigned int)u) << 16; return c.f;
}
__device__ __forceinline__ bfraw f2bf(float f) {
    union { float f; unsigned int i; } c; c.f = f;
    unsigned int lsb = (c.i >> 16) & 1;
    c.i += 0x7fffu + lsb;                   // round-to-nearest-even
    return (bfraw)(c.i >> 16);
}

__device__ __forceinline__ void store_out(float* p, float v) { *p = v; }
__device__ __forceinline__ void store_out(bfraw* p, float v) { *p = f2bf(v); }

// ---------------- block reductions (256 threads = 4 waves), smem passed in ----------
__device__ __forceinline__ float block_sum256(float v, float* sb) {
#pragma unroll
    for (int off = 32; off > 0; off >>= 1) v += __shfl_down(v, off);
    int lane = threadIdx.x & 63, wv = threadIdx.x >> 6;
    __syncthreads();
    if (lane == 0) sb[wv] = v;
    __syncthreads();
    return sb[0] + sb[1] + sb[2] + sb[3];
}

__device__ __forceinline__ void block_sum_max256(float& s, float& m, float* sb) {
#pragma unroll
    for (int off = 32; off > 0; off >>= 1) {
        s += __shfl_down(s, off);
        m = fmaxf(m, __shfl_down(m, off));
    }
    int lane = threadIdx.x & 63, wv = threadIdx.x >> 6;
    __syncthreads();
    if (lane == 0) { sb[wv] = s; sb[4 + wv] = m; }
    __syncthreads();
    s = sb[0] + sb[1] + sb[2] + sb[3];
    m = fmaxf(fmaxf(sb[4], sb[5]), fmaxf(sb[6], sb[7]));
}

// ---------------- device helpers shared by fused and discrete paths ----------------

// weight |W| partial sum for unit u (0..511): weight u>>7, slice u&127
__device__ __forceinline__ void wstats1_body(int u, const float* Wi, const float* Wf,
                                             const float* Wg, const float* Wo,
                                             float* wpart, float* red) {
    int w = u >> 7, slice = u & 127;
    const float* W = (w == 0) ? Wi : ((w == 1) ? Wf : ((w == 2) ? Wg : Wo));
    const float4* p = (const float4*)(W + (size_t)slice * (WELEM / 128));
    float s = 0.f;
    for (int i = threadIdx.x; i < (WELEM / 128 / 4); i += 256) {
        float4 v = p[i];
        s += fabsf(v.x) + fabsf(v.y) + fabsf(v.z) + fabsf(v.w);
    }
    s = block_sum256(s, red);
    if (threadIdx.x == 0) wpart[u] = s;
}

// quant unit: 0..16383 weight float4-groups, 16384..24575 act rows
__device__ __forceinline__ void quant_body(int unit, const float* Wi, const float* Wf,
                                           const float* Wg, const float* Wo,
                                           const float* wdq, int8_t* wq,
                                           const float* x, int8_t* xq, float* adeq,
                                           float* red) {
    int tid = threadIdx.x;
    if (unit < 16384) {
        int w = unit >> 12;                               // 4096 units per weight
        size_t g = ((size_t)(unit & 4095)) * 256 + tid;   // float4 group index
        const float* W = (w == 0) ? Wi : ((w == 1) ? Wf : ((w == 2) ? Wg : Wo));
        float inv = 1.0f / wdq[w];
        float4 v = ((const float4*)W)[g];
        int q0 = (int)rintf(v.x * inv); q0 = q0 < -1 ? -1 : (q0 > 1 ? 1 : q0);
        int q1 = (int)rintf(v.y * inv); q1 = q1 < -1 ? -1 : (q1 > 1 ? 1 : q1);
        int q2 = (int)rintf(v.z * inv); q2 = q2 < -1 ? -1 : (q2 > 1 ? 1 : q2);
        int q3 = (int)rintf(v.w * inv); q3 = q3 < -1 ? -1 : (q3 > 1 ? 1 : q3);
        uint32_t p = (uint32_t)(q0 & 0xff) | ((uint32_t)(q1 & 0xff) << 8) |
                     ((uint32_t)(q2 & 0xff) << 16) | ((uint32_t)(q3 & 0xff) << 24);
        ((uint32_t*)(wq + (size_t)w * WELEM))[g] = p;
        return;
    }
    int row = unit - 16384;
    const float4* xr = (const float4*)(x + (size_t)row * D_DIM);
    float4 a = xr[2 * tid], b = xr[2 * tid + 1];
    float v[8] = {a.x, a.y, a.z, a.w, b.x, b.y, b.z, b.w};
    float ss = 0.f, mx = 0.f;
#pragma unroll
    for (int j = 0; j < 8; j++) { ss += v[j] * v[j]; mx = fmaxf(mx, fabsf(v[j])); }
    block_sum_max256(ss, mx, red);
    float inv = rsqrtf(ss * (1.0f / (float)D_DIM) + 1e-5f);
    float anc = fmaxf(mx * inv, 1e-5f);
    float s = 127.0f / anc;
    if (tid == 0) adeq[row] = anc * (1.0f / 127.0f);
    float sc = inv * s;
    int q[8];
#pragma unroll
    for (int j = 0; j < 8; j++) {
        int t = (int)rintf(v[j] * sc);
        q[j] = t < -128 ? -128 : (t > 127 ? 127 : t);
    }
    uint32_t lo = (uint32_t)(q[0] & 0xff) | ((uint32_t)(q[1] & 0xff) << 8) |
                  ((uint32_t)(q[2] & 0xff) << 16) | ((uint32_t)(q[3] & 0xff) << 24);
    uint32_t hi = (uint32_t)(q[4] & 0xff) | ((uint32_t)(q[5] & 0xff) << 8) |
                  ((uint32_t)(q[6] & 0xff) << 16) | ((uint32_t)(q[7] & 0xff) << 24);
    ((uint2*)(xq + (size_t)row * D_DIM))[tid] = make_uint2(lo, hi);
}

// int8 x ternary GEMM core with XOR-swizzled LDS.
// LDS[row][slot s] holds global chunk (s ^ (row&3)) — the permutation is applied on
// the *global source* per staging lane (global_load_lds LDS dst is lane-linear).
// Readers XOR identically. Breaks the 8-lane start-bank aliasing of the plain layout.
template <typename OutT>
__device__ void gemm_core(const int8_t* A, const int8_t* Bw,
                          const float* adeq, float wsc,
                          int m0, int n0, OutT* Cout,
                          int8_t* sA, int8_t* sB) {
    int tid = threadIdx.x;
    int lane = tid & 63;
    int wv = tid >> 6;
    int wm = (wv & 1) * 64;
    int wn = (wv >> 1) * 128;

    const v4i vzero = {0, 0, 0, 0};
    v4i acc[4][8];
#pragma unroll
    for (int i = 0; i < 4; i++)
#pragma unroll
        for (int j = 0; j < 8; j++) acc[i][j] = vzero;

    int rS = lane >> 2;                               // row within 16-row staging group
    int swz = (((lane & 3) ^ (rS & 3)) << 4);         // permuted source chunk offset
    const int8_t* Ablk = A + (size_t)m0 * K_DIM;
    const int8_t* Bblk = Bw + (size_t)n0 * K_DIM;
    int qq = lane >> 4;                               // quad
    int mr = lane & 15;
    int roff = ((qq ^ (mr & 3)) << 4);                // swizzled read chunk offset

    for (int kt = 0; kt < K_DIM; kt += BKB) {
        gl_lds16(Ablk + (size_t)(wv * 16 + rS) * K_DIM + kt + swz, sA + (wv * 16) * BKB);
        gl_lds16(Ablk + (size_t)(64 + wv * 16 + rS) * K_DIM + kt + swz, sA + (64 + wv * 16) * BKB);
#pragma unroll
        for (int g = 0; g < 4; g++) {
            int rb = g * 64 + wv * 16;
            gl_lds16(Bblk + (size_t)(rb + rS) * K_DIM + kt + swz, sB + rb * BKB);
        }
        __syncthreads();

        v4i afrag[4], bfrag[8];
#pragma unroll
        for (int i = 0; i < 4; i++)
            afrag[i] = *(const v4i*)(sA + (size_t)(wm + i * 16 + mr) * BKB + roff);
#pragma unroll
        for (int j = 0; j < 8; j++)
            bfrag[j] = *(const v4i*)(sB + (size_t)(wn + j * 16 + mr) * BKB + roff);
#pragma unroll
        for (int i = 0; i < 4; i++)
#pragma unroll
            for (int j = 0; j < 8; j++)
                acc[i][j] = __builtin_amdgcn_mfma_i32_16x16x64_i8(afrag[i], bfrag[j], acc[i][j], 0, 0, 0);
        __syncthreads();
    }

    int cc = lane & 15;
#pragma unroll
    for (int i = 0; i < 4; i++) {
#pragma unroll
        for (int r = 0; r < 4; r++) {
            int row = m0 + wm + i * 16 + qq * 4 + r;   // C/D: row = quad*4 + reg
            float rs = adeq[row] * wsc;
            OutT* crow = Cout + (size_t)row * N_DIM + n0 + wn + cc;
#pragma unroll
            for (int j = 0; j < 8; j++) store_out(crow + j * 16, (float)acc[i][j][r] * rs);
        }
    }
}

// scan chunk body: f=sigmoid(fL), i=silu(iL)*(1-f); writes chunk F-product + partial h
__device__ __forceinline__ void scan1_body(int idx, const bfraw* bufI, const bfraw* bufF,
                                           float* Fc, float* Ic) {
    int d = idx & (D_DIM - 1);
    int c = (idx >> 11) & (NCH - 1);
    int b = idx >> 17;
    size_t base = ((size_t)(b * L_DIM + c * CHUNK)) * D_DIM + d;
    float F = 1.f, h = 0.f;
#pragma unroll 4
    for (int t = 0; t < CHUNK; t++) {
        float fr = bf2f(bufF[base + (size_t)t * D_DIM]);
        float ir = bf2f(bufI[base + (size_t)t * D_DIM]);
        float fv = sigmoidf_(fr);
        float iv = ir * sigmoidf_(ir) * (1.0f - fv);
        h = fv * h + iv;
        F *= fv;
    }
    size_t ci = ((size_t)b * NCH + c) * D_DIM + d;
    Fc[ci] = F;
    Ic[ci] = h;
}

__device__ __forceinline__ void scan2_body(int gt, const float* Fc, const float* Ic,
                                           float* Hc) {
    int d = gt & (D_DIM - 1);
    int b = gt >> 11;
    float h = 0.f;
    for (int c0 = 0; c0 < NCH; c0 += 8) {
        float F[8], I[8];
#pragma unroll
        for (int j = 0; j < 8; j++) {
            size_t ci = ((size_t)b * NCH + c0 + j) * D_DIM + d;
            F[j] = Fc[ci];
            I[j] = Ic[ci];
        }
#pragma unroll
        for (int j = 0; j < 8; j++) {
            size_t ci = ((size_t)b * NCH + c0 + j) * D_DIM + d;
            Hc[ci] = h;
            h = F[j] * h + I[j];
        }
    }
}

__device__ __forceinline__ void scan3_body(int idx, const bfraw* bufI, const bfraw* bufF,
                                           const float* Hc, bfraw* hbuf) {
    int d = idx & (D_DIM - 1);
    int c = (idx >> 11) & (NCH - 1);
    int b = idx >> 17;
    size_t base = ((size_t)(b * L_DIM + c * CHUNK)) * D_DIM + d;
    float h = Hc[((size_t)b * NCH + c) * D_DIM + d];
#pragma unroll 4
    for (int t = 0; t < CHUNK; t++) {
        size_t a = base + (size_t)t * D_DIM;
        float fr = bf2f(bufF[a]);
        float ir = bf2f(bufI[a]);
        float fv = sigmoidf_(fr);
        float iv = ir * sigmoidf_(ir) * (1.0f - fv);
        h = fv * h + iv;
        hbuf[a] = f2bf(h);
    }
}

// g-path epilogue + int8 quant of o for one row
__device__ __forceinline__ void gout_body(int row, const bfraw* bufG, const bfraw* hbuf,
                                          const float* gw, int8_t* oq, float* odeq,
                                          float* red) {
    int tid = threadIdx.x;
    union { uint4 u; bfraw s[8]; } g8, h8;
    g8.u = ((const uint4*)(bufG + (size_t)row * D_DIM))[tid];
    float gv[8];
    float ss = 0.f;
#pragma unroll
    for (int j = 0; j < 8; j++) { gv[j] = bf2f(g8.s[j]); ss += gv[j] * gv[j]; }
    float ssg = block_sum256(ss, red);
    float invg = rsqrtf(ssg * (1.0f / (float)D_DIM) + 1e-5f);

    h8.u = ((const uint4*)(hbuf + (size_t)row * D_DIM))[tid];
    const float4* wr = (const float4*)gw;
    float4 w0 = wr[2 * tid], w1 = wr[2 * tid + 1];
    float wv8[8] = {w0.x, w0.y, w0.z, w0.w, w1.x, w1.y, w1.z, w1.w};
    float o[8];
    float sso = 0.f, amax = 0.f;
#pragma unroll
    for (int j = 0; j < 8; j++) {
        float hv = bf2f(h8.s[j]);
        o[j] = gv[j] * invg * wv8[j] * hv * sigmoidf_(hv);
        sso += o[j] * o[j];
        amax = fmaxf(amax, fabsf(o[j]));
    }
    block_sum_max256(sso, amax, red);
    float invo = rsqrtf(sso * (1.0f / (float)D_DIM) + 1e-5f);
    float anc = fmaxf(amax * invo, 1e-5f);
    float s = 127.0f / anc;
    if (tid == 0) odeq[row] = anc * (1.0f / 127.0f);
    float sc = invo * s;
    int q[8];
#pragma unroll
    for (int j = 0; j < 8; j++) {
        int t = (int)rintf(o[j] * sc);
        q[j] = t < -128 ? -128 : (t > 127 ? 127 : t);
    }
    uint32_t lo = (uint32_t)(q[0] & 0xff) | ((uint32_t)(q[1] & 0xff) << 8) |
                  ((uint32_t)(q[2] & 0xff) << 16) | ((uint32_t)(q[3] & 0xff) << 24);
    uint32_t hi = (uint32_t)(q[4] & 0xff) | ((uint32_t)(q[5] & 0xff) << 8) |
                  ((uint32_t)(q[6] & 0xff) << 16) | ((uint32_t)(q[7] & 0xff) << 24);
    ((uint2*)(oq + (size_t)row * D_DIM))[tid] = make_uint2(lo, hi);
}

// ---------------- the whole forward pass as ONE cooperative kernel ----------------
template <int NB>
__global__ __launch_bounds__(256, 2) void hgrn_fused(
    const float* x, const float* Wi, const float* Wf, const float* Wg, const float* Wo,
    const float* gw, float* wpart, float* adeq, float* odeq,
    int8_t* xq, int8_t* wq, float* Fc, float* Ic, float* Hc,
    bfraw* bufI, bfraw* bufF, bfraw* bufG, bfraw* hbuf, float* out) {
    cg::grid_group grid = cg::this_grid();
    __shared__ union {
        struct { int8_t A[BM * BKB]; int8_t B[BN * BKB]; } g;   // 24 KB gemm staging
        float red[16];                                           // reduction scratch
    } sm;

    const int bid = blockIdx.x;
    const int tid = threadIdx.x;
    const int lane = tid & 63, wvi = tid >> 6;

    // ===== Phase W1: per-weight |W| partial sums =====
    for (int u = bid; u < 512; u += NB)
        wstats1_body(u, Wi, Wf, Wg, Wo, wpart, sm.red);
    grid.sync();

    // ===== Phase W2: every block derives wdq[0..3] =====
    float wdq[4];
    {
        float s = wpart[wvi * 128 + lane] + wpart[wvi * 128 + 64 + lane];
#pragma unroll
        for (int off = 32; off > 0; off >>= 1) s += __shfl_down(s, off);
        __syncthreads();
        if (lane == 0) sm.red[wvi] = fmaxf(s * (1.0f / (float)WELEM), 1e-5f);
        __syncthreads();
        wdq[0] = sm.red[0]; wdq[1] = sm.red[1]; wdq[2] = sm.red[2]; wdq[3] = sm.red[3];
        __syncthreads();
    }

    // ===== Phase Q: weight ternary quant + act rmsnorm/int8 quant =====
    for (int unit = bid; unit < 24576; unit += NB)
        quant_body(unit, Wi, Wf, Wg, Wo, wdq, wq, x, xq, adeq, sm.red);
    grid.sync();

    // ===== Phase G1: i/f/g GEMMs (512 tiles per weight) =====
    for (int t = bid; t < 1536; t += NB) {
        int r = t >> 9;
        int tt = t & 511;
        int m0 = (tt & 63) * BM;
        int n0 = (tt >> 6) * BN;
        bfraw* outp = (r == 0) ? bufI : ((r == 1) ? bufF : bufG);
        gemm_core<bfraw>(xq, wq + (size_t)r * WELEM, adeq, wdq[r], m0, n0, outp,
                         sm.g.A, sm.g.B);
    }
    grid.sync();

    // ===== Phase S1: per-chunk scan =====
    for (int u = bid * 256 + tid; u < 524288; u += NB * 256)
        scan1_body(u, bufI, bufF, Fc, Ic);
    grid.sync();

    // ===== Phase S2: inter-chunk scan (first 8192 threads) =====
    {
        int gt = bid * 256 + tid;
        if (gt < 8192) scan2_body(gt, Fc, Ic, Hc);
    }
    grid.sync();

    // ===== Phase S3: replay scan with carry-in =====
    for (int u = bid * 256 + tid; u < 524288; u += NB * 256)
        scan3_body(u, bufI, bufF, Hc, hbuf);
    grid.sync();

    // ===== Phase GQ: o-gate + int8 quant (oq aliases xq) =====
    for (int row = bid; row < 8192; row += NB)
        gout_body(row, bufG, hbuf, gw, xq, odeq, sm.red);
    grid.sync();

    // ===== Phase G2: output GEMM (fp32) =====
    for (int t = bid; t < 512; t += NB) {
        int m0 = (t & 63) * BM;
        int n0 = (t >> 6) * BN;
        gemm_core<float>(xq, wq + 3 * (size_t)WELEM, odeq, wdq[3], m0, n0, out,
                         sm.g.A, sm.g.B);
    }
}

// ---------------- discrete fallback kernels ----------------
__global__ void k_wstats1(const float* Wi, const float* Wf, const float* Wg,
                          const float* Wo, float* wpart) {
    __shared__ float red[16];
    wstats1_body(blockIdx.x, Wi, Wf, Wg, Wo, wpart, red);
}

__global__ void k_wstats2(const float* __restrict__ wpart, float* __restrict__ wdeq) {
    int w = threadIdx.x >> 6;
    int lane = threadIdx.x & 63;
    float s = wpart[w * 128 + lane] + wpart[w * 128 + 64 + lane];
#pragma unroll
    for (int off = 32; off > 0; off >>= 1) s += __shfl_down(s, off);
    if (lane == 0) wdeq[w] = fmaxf(s * (1.0f / (float)WELEM), 1e-5f);
}

__global__ void k_quant(const float* Wi, const float* Wf, const float* Wg,
                        const float* Wo, const float* wdeq, int8_t* wq,
                        const float* x, int8_t* xq, float* adeq) {
    __shared__ float red[16];
    quant_body(blockIdx.x, Wi, Wf, Wg, Wo, wdeq, wq, x, xq, adeq, red);
}

__global__ __launch_bounds__(256, 2) void k_gemm_ifg(
    const int8_t* xq, const int8_t* wq, const float* adeq, const float* wdeq,
    bfraw* bufI, bfraw* bufF, bfraw* bufG) {
    __shared__ int8_t sA[BM * BKB];
    __shared__ int8_t sB[BN * BKB];
    int widx = blockIdx.x >> 3;
    int n0 = (blockIdx.x & 7) * BN;
    int m0 = blockIdx.y * BM;
    bfraw* outp = (widx == 0) ? bufI : ((widx == 1) ? bufF : bufG);
    gemm_core<bfraw>(xq, wq + (size_t)widx * WELEM, adeq, wdeq[widx], m0, n0, outp, sA, sB);
}

__global__ __launch_bounds__(256, 2) void k_gemm_o(
    const int8_t* oq, const int8_t* wq, const float* odeq, const float* wdeq,
    float* out) {
    __shared__ int8_t sA[BM * BKB];
    __shared__ int8_t sB[BN * BKB];
    gemm_core<float>(oq, wq + 3 * (size_t)WELEM, odeq, wdeq[3], blockIdx.y * BM,
                     blockIdx.x * BN, out, sA, sB);
}

__global__ void k_scan1(const bfraw* bufI, const bfraw* bufF, float* Fc, float* Ic) {
    scan1_body(blockIdx.x * 256 + threadIdx.x, bufI, bufF, Fc, Ic);
}

__global__ void k_scan2(const float* Fc, const float* Ic, float* Hc) {
    scan2_body(blockIdx.x * 256 + threadIdx.x, Fc, Ic, Hc);
}

__global__ void k_scan3(const bfraw* bufI, const bfraw* bufF, const float* Hc,
                        bfraw* hbuf) {
    scan3_body(blockIdx.x * 256 + threadIdx.x, bufI, bufF, Hc, hbuf);
}

__global__ void k_gout(const bfraw* bufG, const bfraw* hbuf, const float* gw,
                       int8_t* oq, float* odeq) {
    __shared__ float red[16];
    gout_body(blockIdx.x, bufG, hbuf, gw, oq, odeq, red);
}

// ---------------- driver ----------------
extern "C" void kernel_launch(void* const* d_in, const int* in_sizes, int n_in,
                              void* d_out, int out_size, void* d_ws, size_t ws_size,
                              hipStream_t stream) {
    const float* x  = (const float*)d_in[0];
    const float* Wi = (const float*)d_in[1];
    const float* Wf = (const float*)d_in[2];
    const float* Wg = (const float*)d_in[3];
    const float* Wo = (const float*)d_in[4];
    const float* gw = (const float*)d_in[5];
    float* out = (float*)d_out;

    char* ws = (char*)d_ws;
    float*  wpart = (float*)(ws + 0);                 // 512 partials
    float*  wdeq  = (float*)(ws + 0x8000);            // 4 floats (discrete path)
    float*  adeq  = (float*)(ws + 0x10000);           // 8192 per-row act dequant
    float*  odeq  = (float*)(ws + 0x20000);           // 8192 per-row o dequant
    int8_t* xq    = (int8_t*)(ws + 0x100000);         // 16MB int8 x; reused as oq
    int8_t* wq    = (int8_t*)(ws + 0x1100000);        // 4 x 4MB ternary weights
    float*  Fc    = (float*)(ws + 0x2100000);         // 2MB chunk f-products
    float*  Ic    = (float*)(ws + 0x2300000);         // 2MB chunk partial h
    float*  Hc    = (float*)(ws + 0x2500000);         // 2MB chunk carries
    bfraw*  bufI  = (bfraw*)(ws + 0x4000000);         // 32MB bf16: i_lin
    bfraw*  bufF  = (bfraw*)(ws + 0x6000000);         // 32MB bf16: f_lin
    bfraw*  bufG  = (bfraw*)(ws + 0x8000000);         // 32MB bf16: g_lin
    bfraw*  hbuf  = (bfraw*)(ws + 0xA000000);         // 32MB bf16: h

    void* args[] = {
        (void*)&x, (void*)&Wi, (void*)&Wf, (void*)&Wg, (void*)&Wo, (void*)&gw,
        (void*)&wpart, (void*)&adeq, (void*)&odeq,
        (void*)&xq, (void*)&wq, (void*)&Fc, (void*)&Ic, (void*)&Hc,
        (void*)&bufI, (void*)&bufF, (void*)&bufG, (void*)&hbuf, (void*)&out
    };

    // Capture-safe occupancy query → choose the largest launchable coop grid.
    hipError_t rc = hipErrorUnknown;
    int mab512 = 0, mab256 = 0;
    (void)hipOccupancyMaxActiveBlocksPerMultiprocessor(&mab512, hgrn_fused<512>, 256, 0);
    (void)hipOccupancyMaxActiveBlocksPerMultiprocessor(&mab256, hgrn_fused<256>, 256, 0);
    if (mab512 >= 2) {
        rc = hipLaunchCooperativeKernel((const void*)hgrn_fused<512>, dim3(512),
                                        dim3(256), args, 0, stream);
    } else if (mab256 >= 1) {
        rc = hipLaunchCooperativeKernel((const void*)hgrn_fused<256>, dim3(256),
                                        dim3(256), args, 0, stream);
    }

    if (rc != hipSuccess) {
        // Discrete fallback (round-3 structure, swizzled GEMM cores)
        k_wstats1<<<512, 256, 0, stream>>>(Wi, Wf, Wg, Wo, wpart);
        k_wstats2<<<1, 256, 0, stream>>>(wpart, wdeq);
        k_quant<<<24576, 256, 0, stream>>>(Wi, Wf, Wg, Wo, wdeq, wq, x, xq, adeq);
        k_gemm_ifg<<<dim3(24, M_DIM / BM), 256, 0, stream>>>(xq, wq, adeq, wdeq,
                                                             bufI, bufF, bufG);
        k_scan1<<<2048, 256, 0, stream>>>(bufI, bufF, Fc, Ic);
        k_scan2<<<32, 256, 0, stream>>>(Fc, Ic, Hc);
        k_scan3<<<2048, 256, 0, stream>>>(bufI, bufF, Hc, hbuf);
        k_gout<<<M_DIM, 256, 0, stream>>>(bufG, hbuf, gw, xq /*as oq*/, odeq);
        k_gemm_o<<<dim3(N_DIM / BN, M_DIM / BM), 256, 0, stream>>>(xq /*oq*/, wq,
                                                                   odeq, wdeq, out);
    }

    (void)in_sizes; (void)n_in; (void)out_size; (void)ws_size;
}